// Round 4
// baseline (586.931 us; speedup 1.0000x reference)
//
#include <hip/hip_runtime.h>

// ---------------- problem constants ----------------
#define H_ 96
#define W_ 96
#define NTOK 9216            // H*W
#define CDIM 128
#define HS_ 48               // pooled H
#define NS_ 2304             // pooled tokens
#define LHEADS 4
#define HD_ 16
#define LD_ 64
#define SCALE_ 0.25f
#define KSPLIT 4
#define KEYS_PER_SPLIT 576   // NS_/KSPLIT
#define NPAIR 36864          // LHEADS*NTOK

// ---------------- avg pool 2x2 ----------------
__global__ __launch_bounds__(256)
void k_avgpool(const float* __restrict__ x, float* __restrict__ low) {
    int idx = blockIdx.x * 256 + threadIdx.x;     // over NS_*CDIM
    if (idx >= NS_ * CDIM) return;
    int c = idx & 127;
    int p = idx >> 7;
    int ws_ = p % HS_, hs = p / HS_;
    int base = ((2 * hs) * W_ + 2 * ws_) * CDIM + c;
    float s = x[base] + x[base + CDIM] + x[base + W_ * CDIM] + x[base + W_ * CDIM + CDIM];
    low[idx] = 0.25f * s;
}

// ---------------- high = restore(pixelshuffle(low)) + b - x ----------------
// block: 128 threads (one per out channel), 16 positions per block
__global__ __launch_bounds__(128)
void k_high(const float* __restrict__ x, const float* __restrict__ low,
            const float* __restrict__ rw, const float* __restrict__ rb,
            float* __restrict__ high) {
    __shared__ float w_s[32 * 128];   // w_s[i*128+o] = rw[o*32+i]
    __shared__ float l2h_s[32];
    int o = threadIdx.x;
    for (int idx = o; idx < 32 * 128; idx += 128) {
        int oo = idx >> 5, ii = idx & 31;
        w_s[ii * 128 + oo] = rw[idx];
    }
    float b = rb[o];
    int pos0 = blockIdx.x * 16;
    for (int pp = 0; pp < 16; ++pp) {
        int n = pos0 + pp;
        int h = n / W_, w = n % W_;
        int hs = h >> 1, i = h & 1, ws_ = w >> 1, j = w & 1;
        int off = i * 2 + j;
        __syncthreads();
        if (o < 32) l2h_s[o] = low[(hs * HS_ + ws_) * CDIM + o * 4 + off];
        __syncthreads();
        float acc = 0.f;
        #pragma unroll
        for (int ii = 0; ii < 32; ++ii) acc += l2h_s[ii] * w_s[ii * 128 + o];
        high[n * CDIM + o] = acc + b - x[n * CDIM + o];
    }
}

// ---------------- generic tiled GEMM: C[m, n] = sum_k A[m,k]*Wt[n,k] + bias[n] ----------------
// BM=BN=64, BK=16, 256 threads, 4x4 per thread. M%64==0, N%64==0, K%16==0.
__global__ __launch_bounds__(256)
void k_gemm(const float* __restrict__ A, int lda,
            const float* __restrict__ Wt,          // (N,K) row-major
            const float* __restrict__ bias,        // may be null
            float* __restrict__ C, int ldc,
            int K) {
    __shared__ float As[16][68];
    __shared__ float Bs[16][68];
    int tid = threadIdx.x;
    int tx = tid & 15, ty = tid >> 4;
    int m0 = blockIdx.x * 64, n0 = blockIdx.y * 64;
    int lr = tid >> 2;           // 0..63  (row within tile)
    int lk = (tid & 3) * 4;      // 0,4,8,12 (k4 offset)
    float acc[4][4] = {};
    for (int kk = 0; kk < K; kk += 16) {
        float4 av = *(const float4*)&A[(m0 + lr) * lda + kk + lk];
        float4 bv = *(const float4*)&Wt[(n0 + lr) * K + kk + lk];
        As[lk + 0][lr] = av.x; As[lk + 1][lr] = av.y;
        As[lk + 2][lr] = av.z; As[lk + 3][lr] = av.w;
        Bs[lk + 0][lr] = bv.x; Bs[lk + 1][lr] = bv.y;
        Bs[lk + 2][lr] = bv.z; Bs[lk + 3][lr] = bv.w;
        __syncthreads();
        #pragma unroll
        for (int k = 0; k < 16; ++k) {
            float a[4], bb[4];
            *(float4*)a  = *(const float4*)&As[k][ty * 4];
            *(float4*)bb = *(const float4*)&Bs[k][tx * 4];
            #pragma unroll
            for (int i = 0; i < 4; ++i)
                #pragma unroll
                for (int j = 0; j < 4; ++j) acc[i][j] += a[i] * bb[j];
        }
        __syncthreads();
    }
    #pragma unroll
    for (int i = 0; i < 4; ++i) {
        int m = m0 + ty * 4 + i;
        #pragma unroll
        for (int j = 0; j < 4; ++j) {
            int n = n0 + tx * 4 + j;
            float v = acc[i][j];
            if (bias) v += bias[n];
            C[m * ldc + n] = v;
        }
    }
}

// ---------------- low-freq attention, key-split partial (max-free softmax) ----------------
// grid.x = LHEADS * (NTOK/64) * KSPLIT blocks of 64 threads (1 wave).
// Each thread: one (head, query) pair. K/V rows are WAVE-UNIFORM (scalar path).
// Depth-2 ping-pong register prefetch: loads for pair kk+4/kk+6 issue while
// pairs kk/kk+2 compute -> ~300 cycles of independent work covers scalar-L2
// latency. All buffer indices compile-time constant.
__global__ __launch_bounds__(64)
void k_lattn(const float* __restrict__ lq, const float* __restrict__ lkv,
             float* __restrict__ pacc, float* __restrict__ psum) {
    int bs = blockIdx.x;
    int split = bs % KSPLIT;
    int rest = bs / KSPLIT;
    int head = rest / (NTOK / 64);
    int qb = rest % (NTOK / 64);
    int q = qb * 64 + threadIdx.x;

    float qreg[HD_];
    #pragma unroll
    for (int d = 0; d < HD_; ++d) qreg[d] = lq[q * LD_ + head * HD_ + d] * SCALE_;

    float acc[HD_] = {};
    float lsum = 0.f;

    const float* base = lkv + (size_t)(split * KEYS_PER_SPLIT) * CDIM + head * HD_;

#define LOADPAIR(P, kk) do {                                                  \
    const float* kp_ = base + (size_t)(kk) * CDIM;                            \
    _Pragma("unroll")                                                         \
    for (int d = 0; d < HD_; ++d) {                                           \
        P##k0[d] = kp_[d];           P##k1[d] = kp_[CDIM + d];                \
        P##v0[d] = kp_[LD_ + d];     P##v1[d] = kp_[CDIM + LD_ + d];          \
    }                                                                         \
} while (0)

#define COMPPAIR(P) do {                                                      \
    float s00 = 0.f, s01 = 0.f, s02 = 0.f, s03 = 0.f;                         \
    float s10 = 0.f, s11 = 0.f, s12 = 0.f, s13 = 0.f;                         \
    _Pragma("unroll")                                                         \
    for (int d = 0; d < HD_; d += 4) {                                        \
        s00 += qreg[d + 0] * P##k0[d + 0]; s01 += qreg[d + 1] * P##k0[d + 1]; \
        s02 += qreg[d + 2] * P##k0[d + 2]; s03 += qreg[d + 3] * P##k0[d + 3]; \
        s10 += qreg[d + 0] * P##k1[d + 0]; s11 += qreg[d + 1] * P##k1[d + 1]; \
        s12 += qreg[d + 2] * P##k1[d + 2]; s13 += qreg[d + 3] * P##k1[d + 3]; \
    }                                                                         \
    float e0 = __expf((s00 + s01) + (s02 + s03));                             \
    float e1 = __expf((s10 + s11) + (s12 + s13));                             \
    lsum += e0 + e1;                                                          \
    _Pragma("unroll")                                                         \
    for (int d = 0; d < HD_; ++d) acc[d] += e0 * P##v0[d];                    \
    _Pragma("unroll")                                                         \
    for (int d = 0; d < HD_; ++d) acc[d] += e1 * P##v1[d];                    \
} while (0)

    float Ak0[HD_], Ak1[HD_], Av0[HD_], Av1[HD_];
    float Bk0[HD_], Bk1[HD_], Bv0[HD_], Bv1[HD_];
    LOADPAIR(A, 0);
    LOADPAIR(B, 2);
    // main loop: kk = 0,4,...,568 ; tail computes pairs 572/574 (no OOB loads)
    for (int kk = 0; kk <= KEYS_PER_SPLIT - 8; kk += 4) {
        COMPPAIR(A);
        LOADPAIR(A, kk + 4);
        COMPPAIR(B);
        LOADPAIR(B, kk + 6);
    }
    COMPPAIR(A);
    COMPPAIR(B);
#undef LOADPAIR
#undef COMPPAIR

    int p = head * NTOK + q;
    #pragma unroll
    for (int d = 0; d < HD_; ++d) pacc[(size_t)(split * NPAIR + p) * HD_ + d] = acc[d];
    psum[split * NPAIR + p] = lsum;
}

__global__ __launch_bounds__(256)
void k_lattn_combine(const float* __restrict__ pacc, const float* __restrict__ psum,
                     float* __restrict__ lout) {
    int idx = blockIdx.x * 256 + threadIdx.x;   // over NPAIR*HD_
    if (idx >= NPAIR * HD_) return;
    int p = idx >> 4, d = idx & 15;
    float a = 0.f, s = 0.f;
    #pragma unroll
    for (int sp = 0; sp < KSPLIT; ++sp) a += pacc[(size_t)(sp * NPAIR + p) * HD_ + d];
    #pragma unroll
    for (int sp = 0; sp < KSPLIT; ++sp) s += psum[sp * NPAIR + p];
    int head = p / NTOK, q = p % NTOK;
    lout[q * LD_ + head * HD_ + d] = a / s;
}

// ---------------- high-freq 2x2 windowed attention ----------------
// one thread per (window, head, query-token): 2304*4*4 = 36864
__global__ __launch_bounds__(256)
void k_hattn(const float* __restrict__ qkv, float* __restrict__ ho) {
    int idx = blockIdx.x * 256 + threadIdx.x;
    if (idx >= NPAIR) return;
    int t = idx & 3;
    int hh = (idx >> 2) & 3;
    int g = idx >> 4;
    int gh = g / 48, gw = g % 48;
    int nq = (2 * gh + (t >> 1)) * W_ + 2 * gw + (t & 1);
    float q[HD_];
    #pragma unroll
    for (int d = 0; d < HD_; ++d) q[d] = qkv[nq * 192 + hh * HD_ + d];
    float e[4], esum = 0.f;
    int nk[4];
    #pragma unroll
    for (int kt = 0; kt < 4; ++kt) {
        nk[kt] = (2 * gh + (kt >> 1)) * W_ + 2 * gw + (kt & 1);
        float s = 0.f;
        #pragma unroll
        for (int d = 0; d < HD_; ++d) s += q[d] * qkv[nk[kt] * 192 + 64 + hh * HD_ + d];
        e[kt] = __expf(s * SCALE_);
        esum += e[kt];
    }
    float inv = 1.f / esum;
    float o[HD_] = {};
    #pragma unroll
    for (int kt = 0; kt < 4; ++kt) {
        float pkt = e[kt] * inv;
        #pragma unroll
        for (int d = 0; d < HD_; ++d) o[d] += pkt * qkv[nk[kt] * 192 + 128 + hh * HD_ + d];
    }
    #pragma unroll
    for (int d = 0; d < HD_; ++d) ho[nq * 64 + hh * HD_ + d] = o[d];
}

// ---------------- launch ----------------
extern "C" void kernel_launch(void* const* d_in, const int* in_sizes, int n_in,
                              void* d_out, int out_size, void* d_ws, size_t ws_size,
                              hipStream_t stream) {
    const float* x        = (const float*)d_in[0];
    const float* restore_w = (const float*)d_in[1];
    const float* restore_b = (const float*)d_in[2];
    const float* l_q_w    = (const float*)d_in[3];
    const float* l_kv_w   = (const float*)d_in[4];
    const float* l_proj_w = (const float*)d_in[5];
    const float* l_proj_b = (const float*)d_in[6];
    const float* h_qkv_w  = (const float*)d_in[7];
    const float* h_proj_w = (const float*)d_in[8];
    const float* h_proj_b = (const float*)d_in[9];
    float* out = (float*)d_out;

    float* ws    = (float*)d_ws;
    float* low   = ws;                         // 2304*128   = 294912
    float* high  = low  + 294912;              // 9216*128   = 1179648
    float* lq    = high + 1179648;             // 9216*64    = 589824
    float* lkv   = lq   + 589824;              // 2304*128   = 294912
    float* lout  = lkv  + 294912;              // 9216*64    = 589824
    float* hqkv  = lout + 589824;              // 9216*192   = 1769472
    float* ho    = hqkv + 1769472;             // 9216*64    = 589824
    float* pacc  = ho   + 589824;              // 4*36864*16 = 2359296
    float* psum  = pacc + 2359296;             // 4*36864    = 147456

    // 1. avg pool
    k_avgpool<<<(NS_ * CDIM + 255) / 256, 256, 0, stream>>>(x, low);
    // 2. high-frequency residual
    k_high<<<NTOK / 16, 128, 0, stream>>>(x, low, restore_w, restore_b, high);
    // 3. lq = x @ l_q_w.T            (9216 x 64, K=128)
    k_gemm<<<dim3(NTOK / 64, 1), 256, 0, stream>>>(x, CDIM, l_q_w, nullptr, lq, LD_, CDIM);
    // 4. lkv = low @ l_kv_w.T        (2304 x 128, K=128)
    k_gemm<<<dim3(NS_ / 64, 2), 256, 0, stream>>>(low, CDIM, l_kv_w, nullptr, lkv, CDIM, CDIM);
    // 5. hqkv = high @ h_qkv_w.T     (9216 x 192, K=128)
    k_gemm<<<dim3(NTOK / 64, 3), 256, 0, stream>>>(high, CDIM, h_qkv_w, nullptr, hqkv, 192, CDIM);
    // 6. low attention (key-split partials)
    k_lattn<<<LHEADS * (NTOK / 64) * KSPLIT, 64, 0, stream>>>(lq, lkv, pacc, psum);
    k_lattn_combine<<<(NPAIR * HD_ + 255) / 256, 256, 0, stream>>>(pacc, psum, lout);
    // 7. lx = lout @ l_proj_w.T + b  -> out[:, 0:64]
    k_gemm<<<dim3(NTOK / 64, 1), 256, 0, stream>>>(lout, LD_, l_proj_w, l_proj_b, out, CDIM, LD_);
    // 8. high attention
    k_hattn<<<(NPAIR + 255) / 256, 256, 0, stream>>>(hqkv, ho);
    // 9. hx = ho @ h_proj_w.T + b    -> out[:, 64:128]
    k_gemm<<<dim3(NTOK / 64, 1), 256, 0, stream>>>(ho, LD_, h_proj_w, h_proj_b, out + 64, CDIM, LD_);
}

// Round 5
// 240.288 us; speedup vs baseline: 2.4426x; 2.4426x over previous
//
#include <hip/hip_runtime.h>

// ---------------- problem constants ----------------
#define H_ 96
#define W_ 96
#define NTOK 9216            // H*W
#define CDIM 128
#define HS_ 48               // pooled H
#define NS_ 2304             // pooled tokens
#define LHEADS 4
#define HD_ 16
#define LD_ 64
#define SCALE_ 0.25f
#define KSPLIT 8
#define KEYS_PER_SPLIT 288   // NS_/KSPLIT
#define NPAIR 36864          // LHEADS*NTOK

// ---------------- avg pool 2x2 ----------------
__global__ __launch_bounds__(256)
void k_avgpool(const float* __restrict__ x, float* __restrict__ low) {
    int idx = blockIdx.x * 256 + threadIdx.x;     // over NS_*CDIM
    if (idx >= NS_ * CDIM) return;
    int c = idx & 127;
    int p = idx >> 7;
    int ws_ = p % HS_, hs = p / HS_;
    int base = ((2 * hs) * W_ + 2 * ws_) * CDIM + c;
    float s = x[base] + x[base + CDIM] + x[base + W_ * CDIM] + x[base + W_ * CDIM + CDIM];
    low[idx] = 0.25f * s;
}

// ---------------- high = restore(pixelshuffle(low)) + b - x ----------------
// block: 128 threads (one per out channel), 16 positions per block
__global__ __launch_bounds__(128)
void k_high(const float* __restrict__ x, const float* __restrict__ low,
            const float* __restrict__ rw, const float* __restrict__ rb,
            float* __restrict__ high) {
    __shared__ float w_s[32 * 128];   // w_s[i*128+o] = rw[o*32+i]
    __shared__ float l2h_s[32];
    int o = threadIdx.x;
    for (int idx = o; idx < 32 * 128; idx += 128) {
        int oo = idx >> 5, ii = idx & 31;
        w_s[ii * 128 + oo] = rw[idx];
    }
    float b = rb[o];
    int pos0 = blockIdx.x * 16;
    for (int pp = 0; pp < 16; ++pp) {
        int n = pos0 + pp;
        int h = n / W_, w = n % W_;
        int hs = h >> 1, i = h & 1, ws_ = w >> 1, j = w & 1;
        int off = i * 2 + j;
        __syncthreads();
        if (o < 32) l2h_s[o] = low[(hs * HS_ + ws_) * CDIM + o * 4 + off];
        __syncthreads();
        float acc = 0.f;
        #pragma unroll
        for (int ii = 0; ii < 32; ++ii) acc += l2h_s[ii] * w_s[ii * 128 + o];
        high[n * CDIM + o] = acc + b - x[n * CDIM + o];
    }
}

// ---------------- generic tiled GEMM: C[m, n] = sum_k A[m,k]*Wt[n,k] + bias[n] ----------------
// BM=BN=64, BK=16, 256 threads, 4x4 per thread. M%64==0, N%64==0, K%16==0.
__global__ __launch_bounds__(256)
void k_gemm(const float* __restrict__ A, int lda,
            const float* __restrict__ Wt,          // (N,K) row-major
            const float* __restrict__ bias,        // may be null
            float* __restrict__ C, int ldc,
            int K) {
    __shared__ float As[16][68];
    __shared__ float Bs[16][68];
    int tid = threadIdx.x;
    int tx = tid & 15, ty = tid >> 4;
    int m0 = blockIdx.x * 64, n0 = blockIdx.y * 64;
    int lr = tid >> 2;           // 0..63  (row within tile)
    int lk = (tid & 3) * 4;      // 0,4,8,12 (k4 offset)
    float acc[4][4] = {};
    for (int kk = 0; kk < K; kk += 16) {
        float4 av = *(const float4*)&A[(m0 + lr) * lda + kk + lk];
        float4 bv = *(const float4*)&Wt[(n0 + lr) * K + kk + lk];
        As[lk + 0][lr] = av.x; As[lk + 1][lr] = av.y;
        As[lk + 2][lr] = av.z; As[lk + 3][lr] = av.w;
        Bs[lk + 0][lr] = bv.x; Bs[lk + 1][lr] = bv.y;
        Bs[lk + 2][lr] = bv.z; Bs[lk + 3][lr] = bv.w;
        __syncthreads();
        #pragma unroll
        for (int k = 0; k < 16; ++k) {
            float a[4], bb[4];
            *(float4*)a  = *(const float4*)&As[k][ty * 4];
            *(float4*)bb = *(const float4*)&Bs[k][tx * 4];
            #pragma unroll
            for (int i = 0; i < 4; ++i)
                #pragma unroll
                for (int j = 0; j < 4; ++j) acc[i][j] += a[i] * bb[j];
        }
        __syncthreads();
    }
    #pragma unroll
    for (int i = 0; i < 4; ++i) {
        int m = m0 + ty * 4 + i;
        #pragma unroll
        for (int j = 0; j < 4; ++j) {
            int n = n0 + tx * 4 + j;
            float v = acc[i][j];
            if (bias) v += bias[n];
            C[m * ldc + n] = v;
        }
    }
}

// ---------------- low-freq attention, key-split partial (max-free softmax) ----------------
// grid.x = LHEADS * (NTOK/64) * KSPLIT blocks of 64 threads (1 wave).
// Each thread: one (head, query) pair. K/V rows are WAVE-UNIFORM -> scalar
// (s_load) path; inner loop is v_fmac with one SGPR operand. No LDS.
// Latency-bound -> hidden by TLP: KSPLIT=8 gives 4608 waves (~4.5/SIMD).
// NOTE (round-4 lesson): do NOT software-pipeline this loop — 128 live
// wave-uniform floats exceed the ~102-SGPR file and the compiler demotes
// them (3x regression). Keep the live set at one key-pair (64 floats).
__global__ __launch_bounds__(64)
void k_lattn(const float* __restrict__ lq, const float* __restrict__ lkv,
             float* __restrict__ pacc, float* __restrict__ psum) {
    int bs = blockIdx.x;
    int split = bs % KSPLIT;
    int rest = bs / KSPLIT;
    int head = rest / (NTOK / 64);
    int qb = rest % (NTOK / 64);
    int q = qb * 64 + threadIdx.x;

    float qreg[HD_];
    #pragma unroll
    for (int d = 0; d < HD_; ++d) qreg[d] = lq[q * LD_ + head * HD_ + d] * SCALE_;

    float acc[HD_] = {};
    float lsum = 0.f;

    const int k0 = split * KEYS_PER_SPLIT;
    for (int kk = 0; kk < KEYS_PER_SPLIT; kk += 2) {
        const float* kp = lkv + (size_t)(k0 + kk) * CDIM + head * HD_;  // wave-uniform
        float ka[HD_], kb[HD_];
        #pragma unroll
        for (int d = 0; d < HD_; ++d) { ka[d] = kp[d]; kb[d] = kp[CDIM + d]; }
        float sa0 = 0.f, sa1 = 0.f, sa2 = 0.f, sa3 = 0.f;
        float sb0 = 0.f, sb1 = 0.f, sb2 = 0.f, sb3 = 0.f;
        #pragma unroll
        for (int d = 0; d < HD_; d += 4) {
            sa0 += qreg[d + 0] * ka[d + 0];
            sa1 += qreg[d + 1] * ka[d + 1];
            sa2 += qreg[d + 2] * ka[d + 2];
            sa3 += qreg[d + 3] * ka[d + 3];
            sb0 += qreg[d + 0] * kb[d + 0];
            sb1 += qreg[d + 1] * kb[d + 1];
            sb2 += qreg[d + 2] * kb[d + 2];
            sb3 += qreg[d + 3] * kb[d + 3];
        }
        float va[HD_], vb[HD_];
        #pragma unroll
        for (int d = 0; d < HD_; ++d) { va[d] = kp[LD_ + d]; vb[d] = kp[CDIM + LD_ + d]; }
        float ea = __expf((sa0 + sa1) + (sa2 + sa3));
        float eb = __expf((sb0 + sb1) + (sb2 + sb3));
        lsum += ea + eb;
        #pragma unroll
        for (int d = 0; d < HD_; ++d) acc[d] += ea * va[d];
        #pragma unroll
        for (int d = 0; d < HD_; ++d) acc[d] += eb * vb[d];
    }
    int p = head * NTOK + q;
    #pragma unroll
    for (int d = 0; d < HD_; ++d) pacc[(size_t)(split * NPAIR + p) * HD_ + d] = acc[d];
    psum[(size_t)split * NPAIR + p] = lsum;
}

__global__ __launch_bounds__(256)
void k_lattn_combine(const float* __restrict__ pacc, const float* __restrict__ psum,
                     float* __restrict__ lout) {
    int idx = blockIdx.x * 256 + threadIdx.x;   // over NPAIR*HD_
    if (idx >= NPAIR * HD_) return;
    int p = idx >> 4, d = idx & 15;
    float a = 0.f, s = 0.f;
    #pragma unroll
    for (int sp = 0; sp < KSPLIT; ++sp) a += pacc[(size_t)(sp * NPAIR + p) * HD_ + d];
    #pragma unroll
    for (int sp = 0; sp < KSPLIT; ++sp) s += psum[(size_t)sp * NPAIR + p];
    int head = p / NTOK, q = p % NTOK;
    lout[q * LD_ + head * HD_ + d] = a / s;
}

// ---------------- high-freq 2x2 windowed attention ----------------
// one thread per (window, head, query-token): 2304*4*4 = 36864
__global__ __launch_bounds__(256)
void k_hattn(const float* __restrict__ qkv, float* __restrict__ ho) {
    int idx = blockIdx.x * 256 + threadIdx.x;
    if (idx >= NPAIR) return;
    int t = idx & 3;
    int hh = (idx >> 2) & 3;
    int g = idx >> 4;
    int gh = g / 48, gw = g % 48;
    int nq = (2 * gh + (t >> 1)) * W_ + 2 * gw + (t & 1);
    float q[HD_];
    #pragma unroll
    for (int d = 0; d < HD_; ++d) q[d] = qkv[nq * 192 + hh * HD_ + d];
    float e[4], esum = 0.f;
    int nk[4];
    #pragma unroll
    for (int kt = 0; kt < 4; ++kt) {
        nk[kt] = (2 * gh + (kt >> 1)) * W_ + 2 * gw + (kt & 1);
        float s = 0.f;
        #pragma unroll
        for (int d = 0; d < HD_; ++d) s += q[d] * qkv[nk[kt] * 192 + 64 + hh * HD_ + d];
        e[kt] = __expf(s * SCALE_);
        esum += e[kt];
    }
    float inv = 1.f / esum;
    float o[HD_] = {};
    #pragma unroll
    for (int kt = 0; kt < 4; ++kt) {
        float pkt = e[kt] * inv;
        #pragma unroll
        for (int d = 0; d < HD_; ++d) o[d] += pkt * qkv[nk[kt] * 192 + 128 + hh * HD_ + d];
    }
    #pragma unroll
    for (int d = 0; d < HD_; ++d) ho[nq * 64 + hh * HD_ + d] = o[d];
}

// ---------------- launch ----------------
// Workspace aliasing (floats). pacc (KSPLIT*589824 = 4,718,592) overlaps the
// high-path buffers, which are all dead before k_lattn runs:
//   [0.. )        low    294912   (dead after lkv gemm)
//   [294912..)    high  1179648   (dead after hqkv gemm)
//   [1474560..)   hqkv  1769472   (dead after hattn)
//   [3244032..)   ho     589824   (dead after out_h gemm)
//   pacc  = [0 .. 4718592)            overlaps all of the above
//   psum  = [4718592 .. 5013504)
//   lkv   = [5013504 .. 5308416)      live into lattn
//   lq    = [5308416 .. 5898240)      live into lattn
//   lout  = [5898240 .. 6488064)
// total 6,488,064 floats = 25.95 MB (< 31.3 MB footprint already validated)
extern "C" void kernel_launch(void* const* d_in, const int* in_sizes, int n_in,
                              void* d_out, int out_size, void* d_ws, size_t ws_size,
                              hipStream_t stream) {
    const float* x        = (const float*)d_in[0];
    const float* restore_w = (const float*)d_in[1];
    const float* restore_b = (const float*)d_in[2];
    const float* l_q_w    = (const float*)d_in[3];
    const float* l_kv_w   = (const float*)d_in[4];
    const float* l_proj_w = (const float*)d_in[5];
    const float* l_proj_b = (const float*)d_in[6];
    const float* h_qkv_w  = (const float*)d_in[7];
    const float* h_proj_w = (const float*)d_in[8];
    const float* h_proj_b = (const float*)d_in[9];
    float* out = (float*)d_out;

    float* ws    = (float*)d_ws;
    float* low   = ws;
    float* high  = ws + 294912;
    float* hqkv  = ws + 1474560;
    float* ho    = ws + 3244032;
    float* pacc  = ws;                   // aliases low/high/hqkv/ho (dead by then)
    float* psum  = ws + 4718592;
    float* lkv   = ws + 5013504;
    float* lq    = ws + 5308416;
    float* lout  = ws + 5898240;

    // ---- shared prep ----
    k_avgpool<<<(NS_ * CDIM + 255) / 256, 256, 0, stream>>>(x, low);
    k_high<<<NTOK / 16, 128, 0, stream>>>(x, low, restore_w, restore_b, high);
    // lkv = low @ l_kv_w.T  (2304 x 128, K=128)   [low dead after]
    k_gemm<<<dim3(NS_ / 64, 2), 256, 0, stream>>>(low, CDIM, l_kv_w, nullptr, lkv, CDIM, CDIM);

    // ---- high path first (frees its buffers for pacc) ----
    // hqkv = high @ h_qkv_w.T  (9216 x 192, K=128)   [high dead after]
    k_gemm<<<dim3(NTOK / 64, 3), 256, 0, stream>>>(high, CDIM, h_qkv_w, nullptr, hqkv, 192, CDIM);
    k_hattn<<<(NPAIR + 255) / 256, 256, 0, stream>>>(hqkv, ho);          // [hqkv dead]
    // hx = ho @ h_proj_w.T + b -> out[:, 64:128]      [ho dead after]
    k_gemm<<<dim3(NTOK / 64, 1), 256, 0, stream>>>(ho, LD_, h_proj_w, h_proj_b, out + 64, CDIM, LD_);

    // ---- low path ----
    // lq = x @ l_q_w.T  (9216 x 64, K=128)
    k_gemm<<<dim3(NTOK / 64, 1), 256, 0, stream>>>(x, CDIM, l_q_w, nullptr, lq, LD_, CDIM);
    k_lattn<<<LHEADS * (NTOK / 64) * KSPLIT, 64, 0, stream>>>(lq, lkv, pacc, psum);
    k_lattn_combine<<<(NPAIR * HD_ + 255) / 256, 256, 0, stream>>>(pacc, psum, lout);
    // lx = lout @ l_proj_w.T + b -> out[:, 0:64]
    k_gemm<<<dim3(NTOK / 64, 1), 256, 0, stream>>>(lout, LD_, l_proj_w, l_proj_b, out, CDIM, LD_);
}